// Round 8
// baseline (2041.876 us; speedup 1.0000x reference)
//
#include <hip/hip_runtime.h>
#include <hip/hip_bf16.h>

#define BB 128
#define SS 16
#define EE 512
#define RR 500
#define G4 2048          // 4*E
#define OUT0 64128       // B*501 : scores chunk first
#define NSC 501          // R+1
#define NPAIR 2047       // init pair rows m=0..2046 (p==15 junk, never read)
#define NSU 1012         // 500 scores | 512 u

__device__ __forceinline__ float sigm(float x) { return 1.f / (1.f + expf(-x)); }

// ================= device-global pipeline buffers =================
__device__ float g_blstm[G4];
__device__ float g_blstmr[G4];           // gate-interleaved bias: [4e+gate]
__device__ float g_wihr[G4 * EE];        // gate-interleaved wih rows
__device__ float g_whhr[G4 * EE];        // gate-interleaved whh rows
__device__ float g_fcw[EE + 4];          // fc_w, fc_b at [EE]
__device__ float g_qbias[1024];          // fcq_b | fck_b
__device__ float g_Krel[RR * EE];
__device__ float g_cur[BB * SS * EE];    // physical rows, never shifted
__device__ float g_G[BB * SS * G4];      // QUAD layout: row*2048 + 4e+gate (includes bias)
__device__ float g_h1[BB * SS * EE];
__device__ float g_c1[BB * SS * EE];
__device__ float g_h2[BB * SS * EE];     // pair keyed by physical row of left elem
__device__ float g_sc[BB * SS];          // LOGICAL pair index; RAW score (pre-sigmoid, no bias)
__device__ float g_ent[BB * SS];
__device__ int   g_sel[BB];
__device__ int   g_ord[BB * SS];         // logical pos -> physical row
// attention precomputes + fused buffers
__device__ float g_fckwT[EE * EE];
__device__ float g_fcqwT[EE * EE];
__device__ float g_W2[RR * EE];
__device__ float g_Mx[EE * EE];
__device__ float g_c2[RR + 4];
__device__ float g_v1[EE];
__device__ float g_c0[1];
__device__ float g_su[BB * NSU];

// ================= setup =================
__global__ void k_prep(const float* __restrict__ bih, const float* __restrict__ bhh,
                       const float* __restrict__ fcwv, const float* __restrict__ fcbv,
                       const float* __restrict__ fcqb, const float* __restrict__ fckb) {
    int i = blockIdx.x * blockDim.x + threadIdx.x;   // 2048
    if (i < G4) g_blstm[i] = bih[i] + bhh[i];
    if (i < EE) {
        g_fcw[i] = fcwv[i];
        g_qbias[i] = fcqb[i];
        g_qbias[EE + i] = fckb[i];
    }
    if (i == 0) g_fcw[EE] = fcbv[0];
    if (i < BB * SS) g_ord[i] = i;
}

// gate-interleave reorder: original row n = gate*512+e  ->  row n' = 4e+gate
__global__ void k_reord(const float* __restrict__ wih, const float* __restrict__ whh) {
    int i = blockIdx.x * blockDim.x + threadIdx.x;   // 2048*512
    if (i >= G4 * EE) return;
    int n = i >> 9;
    int k = i & (EE - 1);
    int e = n & (EE - 1);
    int gate = n >> 9;
    int np = 4 * e + gate;
    g_wihr[(size_t)np * EE + k] = wih[i];
    g_whhr[(size_t)np * EE + k] = whh[i];
    if (k == 0) g_blstmr[np] = g_blstm[n];
}

__global__ void k_gather(const int* __restrict__ tok, const float* __restrict__ emb) {
    int i = blockIdx.x * blockDim.x + threadIdx.x;
    if (i >= BB * SS * EE) return;
    int e = i & (EE - 1);
    int r = i >> 9;
    int t = tok[r];
    g_cur[i] = emb[(size_t)t * EE + e];
}

// transpose both fckw and fcqw (enables coalesced staging in kg_W2/kg_Mx)
__global__ void k_tr(const float* __restrict__ fckw, const float* __restrict__ fcqw) {
    int i = blockIdx.x * blockDim.x + threadIdx.x;   // 512*512
    if (i >= EE * EE) return;
    int ep = i >> 9;
    int f = i & (EE - 1);
    g_fckwT[(size_t)f * EE + ep] = fckw[(size_t)ep * EE + f];
    g_fcqwT[(size_t)f * EE + ep] = fcqw[(size_t)ep * EE + f];
}

__global__ __launch_bounds__(512) void k_vprep(const float* __restrict__ fcqw, const float* __restrict__ fckw) {
    __shared__ float sh[512];
    int t = threadIdx.x;
    int blk = blockIdx.x;
    if (blk == 0) {
        float acc = 0.f;
        for (int ep = 0; ep < EE; ep++)
            acc += g_qbias[ep] * fckw[(size_t)ep * EE + t] + g_qbias[EE + ep] * fcqw[(size_t)ep * EE + t];
        g_v1[t] = acc;
    } else if (blk == 1) {
        sh[t] = g_qbias[t] * g_qbias[EE + t];
        __syncthreads();
        for (int s = 256; s > 0; s >>= 1) { if (t < s) sh[t] += sh[t + s]; __syncthreads(); }
        if (t == 0) g_c0[0] = sh[0];
    } else {
        int k = blk - 2;
        sh[t] = g_Krel[(size_t)k * EE + t] * g_qbias[t];
        __syncthreads();
        for (int s = 256; s > 0; s >>= 1) { if (t < s) sh[t] += sh[t + s]; __syncthreads(); }
        if (t == 0) g_c2[k] = sh[0];
    }
}

// ====== fp32 GEMM tile core (setup GEMMs), LDS double-buffered (1 barrier/phase) ======
#define TM 32
#define TN 64
#define TK 32
__device__ __forceinline__ void gemm_dev(
    const float* __restrict__ A, int lda,
    const float* __restrict__ W, int ldw,
    const float* __restrict__ bias, const float* __restrict__ Dadd, int ldd,
    float* __restrict__ C, int ldc, int M, int N, int K)
{
    __shared__ __align__(16) float As[2][TK][TM + 2];
    __shared__ __align__(16) float Ws[2][TK][TN + 4];
    int tid = threadIdx.x;
    int mt = blockIdx.y * TM;
    int nt = blockIdx.x * TN;
    int tr = tid >> 4;
    int tc = tid & 15;
    float acc[2][4] = {{0.f,0.f,0.f,0.f},{0.f,0.f,0.f,0.f}};

    int ea = tid * 4;
    int ra = ea >> 5;
    int ka = ea & 31;
    int gmA = mt + ra;
    bool rokA = gmA < M;
    const float* Arow = A + (size_t)(rokA ? gmA : 0) * lda;
    int ew = tid * 8;
    int rw = ew >> 5;
    int kw = ew & 31;
    int gnW = nt + rw;
    bool rokW = gnW < N;
    const float* Wrow = W + (size_t)(rokW ? gnW : 0) * ldw;

    float4 pa = {0,0,0,0}, pw0 = {0,0,0,0}, pw1 = {0,0,0,0};
    if (rokA) pa = *(const float4*)&Arow[ka];
    if (rokW) { pw0 = *(const float4*)&Wrow[kw]; pw1 = *(const float4*)&Wrow[kw + 4]; }
    As[0][ka + 0][ra] = pa.x; As[0][ka + 1][ra] = pa.y; As[0][ka + 2][ra] = pa.z; As[0][ka + 3][ra] = pa.w;
    Ws[0][kw + 0][rw] = pw0.x; Ws[0][kw + 1][rw] = pw0.y; Ws[0][kw + 2][rw] = pw0.z; Ws[0][kw + 3][rw] = pw0.w;
    Ws[0][kw + 4][rw] = pw1.x; Ws[0][kw + 5][rw] = pw1.y; Ws[0][kw + 6][rw] = pw1.z; Ws[0][kw + 7][rw] = pw1.w;
    __syncthreads();

    int P = K / TK;
    for (int p = 0; p < P; p++) {
        int cur = p & 1;
        bool more = (p + 1) < P;
        if (more) {
            int k2 = (p + 1) * TK;
            if (rokA) pa = *(const float4*)&Arow[k2 + ka];
            if (rokW) { pw0 = *(const float4*)&Wrow[k2 + kw]; pw1 = *(const float4*)&Wrow[k2 + kw + 4]; }
        }
        #pragma unroll
        for (int kk = 0; kk < TK; kk++) {
            const float2 a = *(const float2*)&As[cur][kk][2 * tr];
            const float4 w = *(const float4*)&Ws[cur][kk][4 * tc];
            acc[0][0] += a.x * w.x; acc[0][1] += a.x * w.y; acc[0][2] += a.x * w.z; acc[0][3] += a.x * w.w;
            acc[1][0] += a.y * w.x; acc[1][1] += a.y * w.y; acc[1][2] += a.y * w.z; acc[1][3] += a.y * w.w;
        }
        if (more) {
            int nxt = cur ^ 1;
            As[nxt][ka + 0][ra] = pa.x; As[nxt][ka + 1][ra] = pa.y; As[nxt][ka + 2][ra] = pa.z; As[nxt][ka + 3][ra] = pa.w;
            Ws[nxt][kw + 0][rw] = pw0.x; Ws[nxt][kw + 1][rw] = pw0.y; Ws[nxt][kw + 2][rw] = pw0.z; Ws[nxt][kw + 3][rw] = pw0.w;
            Ws[nxt][kw + 4][rw] = pw1.x; Ws[nxt][kw + 5][rw] = pw1.y; Ws[nxt][kw + 6][rw] = pw1.z; Ws[nxt][kw + 7][rw] = pw1.w;
        }
        __syncthreads();
    }
    #pragma unroll
    for (int i = 0; i < 2; i++) {
        int gm = mt + 2 * tr + i;
        if (gm >= M) continue;
        #pragma unroll
        for (int j = 0; j < 4; j++) {
            int gn = nt + 4 * tc + j;
            if (gn >= N) continue;
            float v = (i == 0) ? ((j == 0) ? acc[0][0] : (j == 1) ? acc[0][1] : (j == 2) ? acc[0][2] : acc[0][3])
                               : ((j == 0) ? acc[1][0] : (j == 1) ? acc[1][1] : (j == 2) ? acc[1][2] : acc[1][3]);
            if (bias) v += bias[gn];
            if (Dadd) v += Dadd[(size_t)gm * ldd + gn];
            C[(size_t)gm * ldc + gn] = v;
        }
    }
}

// ============ big fused fp32 GEMM: 128x128 tile, 8x8 micro, LDS double-buffered ============
// 8x8 micro: 4 b128 LDS reads / 64 FMA-instr = 0.75 LDS-cyc/FMA (vs 1.125 for 8x4).
// Double-buffer removes the second barrier: loads for phase p+1 issue before the FMA
// block and land in the other buffer after it -> staging hidden under FMA, 1 barrier/phase.
// MODE 0: G = cur@wihr + b, fused h1/c1 epilogue (M=2048).
// MODE 1: g2 = h1@whhr + G[row+1], fused h2 epilogue, g2 never stored (M=2047).
#define UM 128
#define UN 128
#define UK 32
template<int MODE>
__global__ __launch_bounds__(256) void kg_bigF() {
    __shared__ __align__(16) float As[2][UK][UM + 4];   // 2 x 16.9 KB
    __shared__ __align__(16) float Ws[2][UK][UN + 4];
    const float* __restrict__ A = (MODE == 0) ? g_cur : g_h1;
    const float* __restrict__ W = (MODE == 0) ? g_wihr : g_whhr;
    const int M = (MODE == 0) ? (BB * SS) : NPAIR;
    int tid = threadIdx.x;          // 256
    int mt = blockIdx.y * UM;
    int nt = blockIdx.x * UN;
    int tr = tid >> 4;              // 0..15
    int tc = tid & 15;              // 0..15
    float acc[8][8] = {};

    int ra = tid & 127;             // row within tile
    int ka = (tid >> 7) << 4;       // 0 or 16: 16 consecutive k per thread
    int gmA = mt + ra;
    bool rokA = gmA < M;
    const float* Arow = A + (size_t)(rokA ? gmA : 0) * EE;
    const float* Wrow = W + (size_t)(nt + ra) * EE;   // N = 2048 always full

    float4 pa[4] = {};
    float4 pw[4];
    #pragma unroll
    for (int j = 0; j < 4; j++) {
        if (rokA) pa[j] = *(const float4*)&Arow[ka + 4 * j];
        pw[j] = *(const float4*)&Wrow[ka + 4 * j];
    }
    #pragma unroll
    for (int j = 0; j < 4; j++) {
        As[0][ka + 4 * j + 0][ra] = pa[j].x;
        As[0][ka + 4 * j + 1][ra] = pa[j].y;
        As[0][ka + 4 * j + 2][ra] = pa[j].z;
        As[0][ka + 4 * j + 3][ra] = pa[j].w;
        Ws[0][ka + 4 * j + 0][ra] = pw[j].x;
        Ws[0][ka + 4 * j + 1][ra] = pw[j].y;
        Ws[0][ka + 4 * j + 2][ra] = pw[j].z;
        Ws[0][ka + 4 * j + 3][ra] = pw[j].w;
    }
    __syncthreads();

    const int P = EE / UK;   // 16
    for (int p = 0; p < P; p++) {
        int cur = p & 1;
        bool more = (p + 1) < P;
        if (more) {
            int k2 = (p + 1) * UK + ka;
            #pragma unroll
            for (int j = 0; j < 4; j++) {
                if (rokA) pa[j] = *(const float4*)&Arow[k2 + 4 * j];
                pw[j] = *(const float4*)&Wrow[k2 + 4 * j];
            }
        }
        #pragma unroll
        for (int kk = 0; kk < UK; kk++) {
            const float4 aA = *(const float4*)&As[cur][kk][4 * tr];
            const float4 aB = *(const float4*)&As[cur][kk][64 + 4 * tr];
            const float4 wA = *(const float4*)&Ws[cur][kk][4 * tc];
            const float4 wB = *(const float4*)&Ws[cur][kk][64 + 4 * tc];
            const float am[8] = {aA.x, aA.y, aA.z, aA.w, aB.x, aB.y, aB.z, aB.w};
            const float wn[8] = {wA.x, wA.y, wA.z, wA.w, wB.x, wB.y, wB.z, wB.w};
            #pragma unroll
            for (int i = 0; i < 8; i++)
                #pragma unroll
                for (int j = 0; j < 8; j++)
                    acc[i][j] += am[i] * wn[j];
        }
        if (more) {
            int nxt = cur ^ 1;
            #pragma unroll
            for (int j = 0; j < 4; j++) {
                As[nxt][ka + 4 * j + 0][ra] = pa[j].x;
                As[nxt][ka + 4 * j + 1][ra] = pa[j].y;
                As[nxt][ka + 4 * j + 2][ra] = pa[j].z;
                As[nxt][ka + 4 * j + 3][ra] = pa[j].w;
                Ws[nxt][ka + 4 * j + 0][ra] = pw[j].x;
                Ws[nxt][ka + 4 * j + 1][ra] = pw[j].y;
                Ws[nxt][ka + 4 * j + 2][ra] = pw[j].z;
                Ws[nxt][ka + 4 * j + 3][ra] = pw[j].w;
            }
        }
        __syncthreads();
    }

    // fused epilogue: cols nt+4tc..+3 and nt+64+4tc..+3 are complete gate quads
    int c0 = nt + 4 * tc;
    int c1c = c0 + 64;
    int e0 = (nt >> 2) + tc;        // quad index of c0; quad of c1c is e0+16
    #pragma unroll
    for (int ri = 0; ri < 8; ri++) {
        int row = (ri < 4) ? (4 * tr + ri) : (60 + 4 * tr + ri);
        int gm = mt + row;
        if (gm >= M) continue;
        float q0x = acc[ri][0], q0y = acc[ri][1], q0z = acc[ri][2], q0w = acc[ri][3];
        float q1x = acc[ri][4], q1y = acc[ri][5], q1z = acc[ri][6], q1w = acc[ri][7];
        if (MODE == 0) {
            const float4 b0 = *(const float4*)&g_blstmr[c0];
            const float4 b1 = *(const float4*)&g_blstmr[c1c];
            q0x += b0.x; q0y += b0.y; q0z += b0.z; q0w += b0.w;
            q1x += b1.x; q1y += b1.y; q1z += b1.z; q1w += b1.w;
            float4 o0 = {q0x, q0y, q0z, q0w};
            float4 o1 = {q1x, q1y, q1z, q1w};
            *(float4*)&g_G[(size_t)gm * G4 + c0]  = o0;
            *(float4*)&g_G[(size_t)gm * G4 + c1c] = o1;
            float cA = sigm(q0x) * tanhf(q0z);
            g_c1[(size_t)gm * EE + e0] = cA;
            g_h1[(size_t)gm * EE + e0] = sigm(q0w) * tanhf(cA);
            float cB = sigm(q1x) * tanhf(q1z);
            g_c1[(size_t)gm * EE + e0 + 16] = cB;
            g_h1[(size_t)gm * EE + e0 + 16] = sigm(q1w) * tanhf(cB);
        } else {
            const float4 d0 = *(const float4*)&g_G[(size_t)(gm + 1) * G4 + c0];
            const float4 d1 = *(const float4*)&g_G[(size_t)(gm + 1) * G4 + c1c];
            q0x += d0.x; q0y += d0.y; q0z += d0.z; q0w += d0.w;
            q1x += d1.x; q1y += d1.y; q1z += d1.z; q1w += d1.w;
            float c1a = g_c1[(size_t)gm * EE + e0];
            float c1b = g_c1[(size_t)gm * EE + e0 + 16];
            float cA = sigm(q0y) * c1a + sigm(q0x) * tanhf(q0z);
            g_h2[(size_t)gm * EE + e0] = sigm(q0w) * tanhf(cA);
            float cB = sigm(q1y) * c1b + sigm(q1x) * tanhf(q1z);
            g_h2[(size_t)gm * EE + e0 + 16] = sigm(q1w) * tanhf(cB);
        }
    }
}

// ---- full GEMM wrappers (attention precompute; all coalesced row-major W) ----
__global__ __launch_bounds__(256) void kg_Krel(const float* __restrict__ emb, const float* __restrict__ fckw) {
    gemm_dev(emb, EE, fckw, EE, g_qbias + EE, nullptr, 0, g_Krel, EE, RR, EE, EE);
}
__global__ __launch_bounds__(256) void kg_W2() {
    gemm_dev(g_Krel, EE, g_fcqwT, EE, nullptr, nullptr, 0, g_W2, EE, RR, EE, EE);
}
__global__ __launch_bounds__(256) void kg_Mx() {
    gemm_dev(g_fckwT, EE, g_fcqwT, EE, nullptr, nullptr, 0, g_Mx, EE, EE, EE, EE);
}

// ---- init score: raw dot h2 . fcw  (sigmoid+bias monotone -> argmax-equivalent) ----
__global__ __launch_bounds__(256) void k_scI() {
    int m = blockIdx.x;                 // 0..2046
    int t = threadIdx.x;
    __shared__ float red[256];
    const float* h = g_h2 + (size_t)m * EE;
    float part = h[t] * g_fcw[t] + h[t + 256] * g_fcw[t + 256];
    red[t] = part;
    __syncthreads();
    for (int s = 128; s > 0; s >>= 1) { if (t < s) red[t] += red[t + s]; __syncthreads(); }
    if (t == 0) g_sc[m] = red[0];
}

// ---- per-iter score for the 2 changed pairs ----
__global__ __launch_bounds__(256) void k_scP(int L) {
    int m = blockIdx.x;                 // 0..255
    int b = m >> 1;
    int tcand = m & 1;
    int s = g_sel[b];
    int p = s - 1 + tcand;
    bool valid = tcand == 0 ? (s >= 1) : (s <= L - 3);
    if (!valid) return;
    int physL = g_ord[b * SS + p];
    int t = threadIdx.x;
    __shared__ float red[256];
    const float* h = g_h2 + (size_t)physL * EE;
    float part = h[t] * g_fcw[t] + h[t + 256] * g_fcw[t + 256];
    red[t] = part;
    __syncthreads();
    for (int s2 = 128; s2 > 0; s2 >>= 1) { if (t < s2) red[t] += red[t + s2]; __syncthreads(); }
    if (t == 0) g_sc[b * SS + p] = red[0];
}

// ---- fused argmax + scores|u GEMM (double-buffered) ----
__global__ __launch_bounds__(256) void kg_su(int P) {
    __shared__ __align__(16) float As[2][TK][TM + 2];
    __shared__ __align__(16) float Ws[2][TK][TN + 4];
    __shared__ int s_phys[TM];
    int tid = threadIdx.x;
    int mt = blockIdx.y * TM;
    int nt = blockIdx.x * TN;
    int tr = tid >> 4;
    int tc = tid & 15;
    float acc[2][4] = {{0.f,0.f,0.f,0.f},{0.f,0.f,0.f,0.f}};

    if (tid < TM) {
        int b = mt + tid;                    // M = BB exact
        float best = -1e30f; int bi = 0;
        for (int p = 0; p < P; p++) {
            float v = g_sc[b * SS + p];
            if (v > best) { best = v; bi = p; }
        }
        s_phys[tid] = g_ord[b * SS + bi];
        if (blockIdx.x == 0) g_sel[b] = bi;
    }
    __syncthreads();

    int ea = tid * 4;
    int ra = ea >> 5;
    int ka = ea & 31;
    const float* Arow = g_h2 + (size_t)s_phys[ra] * EE;
    int ew = tid * 8;
    int rw = ew >> 5;
    int kw = ew & 31;
    int gnW = nt + rw;
    bool rokW = gnW < NSU;
    const float* Wrow = nullptr;
    if (rokW) Wrow = (gnW < RR) ? (g_W2 + (size_t)gnW * EE) : (g_Mx + (size_t)(gnW - RR) * EE);

    float4 pa = *(const float4*)&Arow[ka];
    float4 pw0 = {0,0,0,0}, pw1 = {0,0,0,0};
    if (rokW) { pw0 = *(const float4*)&Wrow[kw]; pw1 = *(const float4*)&Wrow[kw + 4]; }
    As[0][ka + 0][ra] = pa.x; As[0][ka + 1][ra] = pa.y; As[0][ka + 2][ra] = pa.z; As[0][ka + 3][ra] = pa.w;
    Ws[0][kw + 0][rw] = pw0.x; Ws[0][kw + 1][rw] = pw0.y; Ws[0][kw + 2][rw] = pw0.z; Ws[0][kw + 3][rw] = pw0.w;
    Ws[0][kw + 4][rw] = pw1.x; Ws[0][kw + 5][rw] = pw1.y; Ws[0][kw + 6][rw] = pw1.z; Ws[0][kw + 7][rw] = pw1.w;
    __syncthreads();

    const int NP = EE / TK;
    for (int p = 0; p < NP; p++) {
        int cur = p & 1;
        bool more = (p + 1) < NP;
        if (more) {
            int k2 = (p + 1) * TK;
            pa = *(const float4*)&Arow[k2 + ka];
            if (rokW) { pw0 = *(const float4*)&Wrow[k2 + kw]; pw1 = *(const float4*)&Wrow[k2 + kw + 4]; }
        }
        #pragma unroll
        for (int kk = 0; kk < TK; kk++) {
            const float2 a = *(const float2*)&As[cur][kk][2 * tr];
            const float4 w = *(const float4*)&Ws[cur][kk][4 * tc];
            acc[0][0] += a.x * w.x; acc[0][1] += a.x * w.y; acc[0][2] += a.x * w.z; acc[0][3] += a.x * w.w;
            acc[1][0] += a.y * w.x; acc[1][1] += a.y * w.y; acc[1][2] += a.y * w.z; acc[1][3] += a.y * w.w;
        }
        if (more) {
            int nxt = cur ^ 1;
            As[nxt][ka + 0][ra] = pa.x; As[nxt][ka + 1][ra] = pa.y; As[nxt][ka + 2][ra] = pa.z; As[nxt][ka + 3][ra] = pa.w;
            Ws[nxt][kw + 0][rw] = pw0.x; Ws[nxt][kw + 1][rw] = pw0.y; Ws[nxt][kw + 2][rw] = pw0.z; Ws[nxt][kw + 3][rw] = pw0.w;
            Ws[nxt][kw + 4][rw] = pw1.x; Ws[nxt][kw + 5][rw] = pw1.y; Ws[nxt][kw + 6][rw] = pw1.z; Ws[nxt][kw + 7][rw] = pw1.w;
        }
        __syncthreads();
    }
    #pragma unroll
    for (int i = 0; i < 2; i++) {
        int gm = mt + 2 * tr + i;
        #pragma unroll
        for (int j = 0; j < 4; j++) {
            int gn = nt + 4 * tc + j;
            if (gn >= NSU) continue;
            float v = (i == 0) ? ((j == 0) ? acc[0][0] : (j == 1) ? acc[0][1] : (j == 2) ? acc[0][2] : acc[0][3])
                               : ((j == 0) ? acc[1][0] : (j == 1) ? acc[1][1] : (j == 2) ? acc[1][2] : acc[1][3]);
            g_su[(size_t)gm * NSU + gn] = v + (gn < RR ? g_c2[gn] : 0.f);
        }
    }
}

// ---- incremental fused GEMM: G/h1/c1 for merged row; M=BB (double-buffered) ----
__global__ __launch_bounds__(256) void kg_GiF() {
    __shared__ __align__(16) float As[2][TK][TM + 2];
    __shared__ __align__(16) float Ws[2][TK][TN + 4];
    __shared__ int s_phys[TM];
    int tid = threadIdx.x;
    int mt = blockIdx.y * TM;
    int nt = blockIdx.x * TN;
    int tr = tid >> 4;
    int tc = tid & 15;
    float acc[2][4] = {{0.f,0.f,0.f,0.f},{0.f,0.f,0.f,0.f}};

    if (tid < TM) {
        int b = mt + tid;
        s_phys[tid] = g_ord[b * SS + g_sel[b]];
    }
    __syncthreads();

    int ea = tid * 4;
    int ra = ea >> 5;
    int ka = ea & 31;
    const float* Arow = g_cur + (size_t)s_phys[ra] * EE;
    int ew = tid * 8;
    int rw = ew >> 5;
    int kw = ew & 31;
    const float* Wrow = g_wihr + (size_t)(nt + rw) * EE;

    float4 pa = *(const float4*)&Arow[ka];
    float4 pw0 = *(const float4*)&Wrow[kw];
    float4 pw1 = *(const float4*)&Wrow[kw + 4];
    As[0][ka + 0][ra] = pa.x; As[0][ka + 1][ra] = pa.y; As[0][ka + 2][ra] = pa.z; As[0][ka + 3][ra] = pa.w;
    Ws[0][kw + 0][rw] = pw0.x; Ws[0][kw + 1][rw] = pw0.y; Ws[0][kw + 2][rw] = pw0.z; Ws[0][kw + 3][rw] = pw0.w;
    Ws[0][kw + 4][rw] = pw1.x; Ws[0][kw + 5][rw] = pw1.y; Ws[0][kw + 6][rw] = pw1.z; Ws[0][kw + 7][rw] = pw1.w;
    __syncthreads();

    const int NP = EE / TK;
    for (int p = 0; p < NP; p++) {
        int cur = p & 1;
        bool more = (p + 1) < NP;
        if (more) {
            int k2 = (p + 1) * TK;
            pa = *(const float4*)&Arow[k2 + ka];
            pw0 = *(const float4*)&Wrow[k2 + kw];
            pw1 = *(const float4*)&Wrow[k2 + kw + 4];
        }
        #pragma unroll
        for (int kk = 0; kk < TK; kk++) {
            const float2 a = *(const float2*)&As[cur][kk][2 * tr];
            const float4 w = *(const float4*)&Ws[cur][kk][4 * tc];
            acc[0][0] += a.x * w.x; acc[0][1] += a.x * w.y; acc[0][2] += a.x * w.z; acc[0][3] += a.x * w.w;
            acc[1][0] += a.y * w.x; acc[1][1] += a.y * w.y; acc[1][2] += a.y * w.z; acc[1][3] += a.y * w.w;
        }
        if (more) {
            int nxt = cur ^ 1;
            As[nxt][ka + 0][ra] = pa.x; As[nxt][ka + 1][ra] = pa.y; As[nxt][ka + 2][ra] = pa.z; As[nxt][ka + 3][ra] = pa.w;
            Ws[nxt][kw + 0][rw] = pw0.x; Ws[nxt][kw + 1][rw] = pw0.y; Ws[nxt][kw + 2][rw] = pw0.z; Ws[nxt][kw + 3][rw] = pw0.w;
            Ws[nxt][kw + 4][rw] = pw1.x; Ws[nxt][kw + 5][rw] = pw1.y; Ws[nxt][kw + 6][rw] = pw1.z; Ws[nxt][kw + 7][rw] = pw1.w;
        }
        __syncthreads();
    }
    int c0 = nt + 4 * tc;
    int e0 = (nt >> 2) + tc;
    const float4 b4 = *(const float4*)&g_blstmr[c0];
    #pragma unroll
    for (int i = 0; i < 2; i++) {
        int phys = s_phys[2 * tr + i];
        float qx = acc[i][0] + b4.x;
        float qy = acc[i][1] + b4.y;
        float qz = acc[i][2] + b4.z;
        float qw = acc[i][3] + b4.w;
        float4 o = {qx, qy, qz, qw};
        *(float4*)&g_G[(size_t)phys * G4 + c0] = o;
        float cA = sigm(qx) * tanhf(qz);
        g_c1[(size_t)phys * EE + e0] = cA;
        g_h1[(size_t)phys * EE + e0] = sigm(qw) * tanhf(cA);
    }
}

// ---- incremental fused GEMM: h2 for 2 candidate pairs/batch; M=2*BB (double-buffered) ----
__global__ __launch_bounds__(256) void kg_g2iF(int L) {
    __shared__ __align__(16) float As[2][TK][TM + 2];
    __shared__ __align__(16) float Ws[2][TK][TN + 4];
    __shared__ int s_physA[TM];
    __shared__ int s_physD[TM];
    __shared__ int s_val[TM];
    int tid = threadIdx.x;
    int mt = blockIdx.y * TM;
    int nt = blockIdx.x * TN;
    int tr = tid >> 4;
    int tc = tid & 15;
    float acc[2][4] = {{0.f,0.f,0.f,0.f},{0.f,0.f,0.f,0.f}};

    if (tid < TM) {
        int gm = mt + tid;
        int b = gm >> 1;
        int tcand = gm & 1;
        int s = g_sel[b];
        int p = min(max(s - 1 + tcand, 0), 14);
        s_physA[tid] = g_ord[b * SS + p];
        s_physD[tid] = g_ord[b * SS + p + 1];
        s_val[tid] = tcand == 0 ? (s >= 1) : (s <= L - 3);
    }
    __syncthreads();

    int ea = tid * 4;
    int ra = ea >> 5;
    int ka = ea & 31;
    const float* Arow = g_h1 + (size_t)s_physA[ra] * EE;
    int ew = tid * 8;
    int rw = ew >> 5;
    int kw = ew & 31;
    const float* Wrow = g_whhr + (size_t)(nt + rw) * EE;

    float4 pa = *(const float4*)&Arow[ka];
    float4 pw0 = *(const float4*)&Wrow[kw];
    float4 pw1 = *(const float4*)&Wrow[kw + 4];
    As[0][ka + 0][ra] = pa.x; As[0][ka + 1][ra] = pa.y; As[0][ka + 2][ra] = pa.z; As[0][ka + 3][ra] = pa.w;
    Ws[0][kw + 0][rw] = pw0.x; Ws[0][kw + 1][rw] = pw0.y; Ws[0][kw + 2][rw] = pw0.z; Ws[0][kw + 3][rw] = pw0.w;
    Ws[0][kw + 4][rw] = pw1.x; Ws[0][kw + 5][rw] = pw1.y; Ws[0][kw + 6][rw] = pw1.z; Ws[0][kw + 7][rw] = pw1.w;
    __syncthreads();

    const int NP = EE / TK;
    for (int p = 0; p < NP; p++) {
        int cur = p & 1;
        bool more = (p + 1) < NP;
        if (more) {
            int k2 = (p + 1) * TK;
            pa = *(const float4*)&Arow[k2 + ka];
            pw0 = *(const float4*)&Wrow[k2 + kw];
            pw1 = *(const float4*)&Wrow[k2 + kw + 4];
        }
        #pragma unroll
        for (int kk = 0; kk < TK; kk++) {
            const float2 a = *(const float2*)&As[cur][kk][2 * tr];
            const float4 w = *(const float4*)&Ws[cur][kk][4 * tc];
            acc[0][0] += a.x * w.x; acc[0][1] += a.x * w.y; acc[0][2] += a.x * w.z; acc[0][3] += a.x * w.w;
            acc[1][0] += a.y * w.x; acc[1][1] += a.y * w.y; acc[1][2] += a.y * w.z; acc[1][3] += a.y * w.w;
        }
        if (more) {
            int nxt = cur ^ 1;
            As[nxt][ka + 0][ra] = pa.x; As[nxt][ka + 1][ra] = pa.y; As[nxt][ka + 2][ra] = pa.z; As[nxt][ka + 3][ra] = pa.w;
            Ws[nxt][kw + 0][rw] = pw0.x; Ws[nxt][kw + 1][rw] = pw0.y; Ws[nxt][kw + 2][rw] = pw0.z; Ws[nxt][kw + 3][rw] = pw0.w;
            Ws[nxt][kw + 4][rw] = pw1.x; Ws[nxt][kw + 5][rw] = pw1.y; Ws[nxt][kw + 6][rw] = pw1.z; Ws[nxt][kw + 7][rw] = pw1.w;
        }
        __syncthreads();
    }
    int c0 = nt + 4 * tc;
    int e0 = (nt >> 2) + tc;
    #pragma unroll
    for (int i = 0; i < 2; i++) {
        int r = 2 * tr + i;
        if (!s_val[r]) continue;
        int pA = s_physA[r];
        int pD = s_physD[r];
        const float4 d4 = *(const float4*)&g_G[(size_t)pD * G4 + c0];
        float qx = acc[i][0] + d4.x;
        float qy = acc[i][1] + d4.y;
        float qz = acc[i][2] + d4.z;
        float qw = acc[i][3] + d4.w;
        float c1v = g_c1[(size_t)pA * EE + e0];
        float cA = sigm(qy) * c1v + sigm(qx) * tanhf(qz);
        g_h2[(size_t)pA * EE + e0] = sigm(qw) * tanhf(cA);
    }
}

// ================= fused softmax + entropy + merged + ord-update (+final output) =================
__global__ __launch_bounds__(512) void k_smu(int col, int finalFlag, int L,
                                             const float* __restrict__ emb, float* __restrict__ out) {
    int b = blockIdx.x;
    int t = threadIdx.x;      // 0..511
    __shared__ float sh[512];
    __shared__ float srow[NSC];
    __shared__ float s_p500;
    const float* su = g_su + (size_t)b * NSU;
    int s = g_sel[b];
    int phys = g_ord[b * SS + s];
    const float* h2row = g_h2 + (size_t)phys * EE;
    const float isq = 0.044194173824159216f;   // 1/sqrt(512)

    float hv = h2row[t];
    sh[t] = hv * (su[RR + t] + g_v1[t]);
    __syncthreads();
    for (int ss = 256; ss > 0; ss >>= 1) { if (t < ss) sh[t] += sh[t + ss]; __syncthreads(); }
    if (t == 0) srow[RR] = (sh[0] + g_c0[0]) * isq;
    __syncthreads();
    if (t < RR) srow[t] = su[t] * isq;
    __syncthreads();
    float mx = (t < NSC) ? srow[t] : -1e30f;
    sh[t] = mx; __syncthreads();
    for (int ss = 256; ss > 0; ss >>= 1) { if (t < ss) sh[t] = fmaxf(sh[t], sh[t + ss]); __syncthreads(); }
    mx = sh[0]; __syncthreads();
    float zp = (t < NSC) ? expf(srow[t] - mx) : 0.f;
    sh[t] = zp; __syncthreads();
    for (int ss = 256; ss > 0; ss >>= 1) { if (t < ss) sh[t] += sh[t + ss]; __syncthreads(); }
    float lse = mx + logf(sh[0]);
    __syncthreads();
    float pb = (t < NSC) ? expf(srow[t] - lse) : 0.f;
    float ep = (t < NSC) ? pb * (lse - srow[t]) : 0.f;
    if (finalFlag && t < NSC) out[(size_t)b * NSC + t] = srow[t];
    sh[t] = ep; __syncthreads();
    for (int ss = 256; ss > 0; ss >>= 1) { if (t < ss) sh[t] += sh[t + ss]; __syncthreads(); }
    if (finalFlag) {
        if (t < 16) {
            float v = (t == 15) ? sh[0] : ((t == 14) ? 0.f : g_ent[b * SS + t]);
            out[OUT0 + b * 16 + t] = v;
        }
        return;
    }
    if (t == 0) g_ent[b * SS + col] = sh[0];

    __syncthreads();
    if (t < NSC) srow[t] = pb;
    if (t == RR) s_p500 = pb;
    __syncthreads();
    float macc = 0.f;
    #pragma unroll 4
    for (int k = 0; k < RR; k++) macc += srow[k] * emb[(size_t)k * EE + t];
    g_cur[(size_t)phys * EE + t] = macc + s_p500 * hv;
    if (t == 0) {
        for (int j = s + 1; j <= L - 2; j++) g_ord[b * SS + j] = g_ord[b * SS + j + 1];
        for (int pp = s + 1; pp <= L - 3; pp++) g_sc[b * SS + pp] = g_sc[b * SS + pp + 1];
    }
}

// ================= host launch =================
extern "C" void kernel_launch(void* const* d_in, const int* in_sizes, int n_in,
                              void* d_out, int out_size, void* d_ws, size_t ws_size,
                              hipStream_t stream) {
    const int*   tokens = (const int*)d_in[0];
    const float* emb    = (const float*)d_in[1];
    const float* wih    = (const float*)d_in[2];
    const float* whh    = (const float*)d_in[3];
    const float* bih    = (const float*)d_in[4];
    const float* bhh    = (const float*)d_in[5];
    const float* fcwv   = (const float*)d_in[6];
    const float* fcbv   = (const float*)d_in[7];
    const float* fcqw   = (const float*)d_in[8];
    const float* fcqb   = (const float*)d_in[9];
    const float* fckw   = (const float*)d_in[10];
    const float* fckb   = (const float*)d_in[11];
    float* out = (float*)d_out;

    auto grid32 = [](int M, int N) { return dim3((unsigned)((N + TN - 1) / TN), (unsigned)((M + TM - 1) / TM)); };

    // ---- setup + attention precomputes (once) ----
    k_prep<<<dim3(8), dim3(256), 0, stream>>>(bih, bhh, fcwv, fcbv, fcqb, fckb);
    k_reord<<<dim3((G4 * EE) / 256), dim3(256), 0, stream>>>(wih, whh);
    kg_Krel<<<grid32(RR, EE), dim3(256), 0, stream>>>(emb, fckw);
    k_tr<<<dim3((EE * EE + 255) / 256), dim3(256), 0, stream>>>(fckw, fcqw);
    kg_W2<<<grid32(RR, EE), dim3(256), 0, stream>>>();
    kg_Mx<<<grid32(EE, EE), dim3(256), 0, stream>>>();
    k_vprep<<<dim3(502), dim3(512), 0, stream>>>(fcqw, fckw);
    k_gather<<<dim3((BB * SS * EE + 255) / 256), dim3(256), 0, stream>>>(tokens, emb);

    // ---- initial full LSTM pass (once; identity order; fused gate epilogues) ----
    kg_bigF<0><<<dim3(16, 16), dim3(256), 0, stream>>>();
    kg_bigF<1><<<dim3(16, 16), dim3(256), 0, stream>>>();
    k_scI<<<dim3(NPAIR), dim3(256), 0, stream>>>();

    for (int L = SS; L >= 3; L--) {
        kg_su<<<grid32(BB, NSU), dim3(256), 0, stream>>>(L - 1);
        k_smu<<<dim3(BB), dim3(512), 0, stream>>>(SS - L, 0, L, emb, out);
        kg_GiF<<<grid32(BB, G4), dim3(256), 0, stream>>>();
        kg_g2iF<<<grid32(2 * BB, G4), dim3(256), 0, stream>>>(L);
        k_scP<<<dim3(2 * BB), dim3(256), 0, stream>>>(L);
    }

    // L == 2: pair 0's h2 is the final x; final k_smu writes scores + loss region
    kg_su<<<grid32(BB, NSU), dim3(256), 0, stream>>>(1);
    k_smu<<<dim3(BB), dim3(512), 0, stream>>>(15, 1, 2, emb, out);

    (void)in_sizes; (void)n_in; (void)out_size; (void)d_ws; (void)ws_size;
}

// Round 9
// 1691.024 us; speedup vs baseline: 1.2075x; 1.2075x over previous
//
#include <hip/hip_runtime.h>
#include <hip/hip_bf16.h>

#define BB 128
#define SS 16
#define EE 512
#define RR 500
#define G4 2048          // 4*E
#define OUT0 64128       // B*501 : scores chunk first
#define NSC 501          // R+1
#define NPAIR 2047       // init pair rows m=0..2046 (p==15 junk, never read)
#define NSU 1012         // 500 scores | 512 u

__device__ __forceinline__ float sigm(float x) { return 1.f / (1.f + expf(-x)); }

// ================= device-global pipeline buffers =================
__device__ float g_blstm[G4];
__device__ float g_blstmr[G4];           // gate-interleaved bias: [4e+gate]
__device__ float g_wihr[G4 * EE];        // gate-interleaved wih rows
__device__ float g_whhr[G4 * EE];        // gate-interleaved whh rows
__device__ float g_fcw[EE + 4];          // fc_w, fc_b at [EE]
__device__ float g_qbias[1024];          // fcq_b | fck_b
__device__ float g_Krel[RR * EE];
__device__ float g_cur[BB * SS * EE];    // physical rows, never shifted
__device__ float g_G[BB * SS * G4];      // QUAD layout: row*2048 + 4e+gate (includes bias)
__device__ float g_h1[BB * SS * EE];
__device__ float g_c1[BB * SS * EE];
__device__ float g_h2[BB * SS * EE];     // pair keyed by physical row of left elem
__device__ float g_sc[BB * SS];          // LOGICAL pair index; RAW score (pre-sigmoid, no bias)
__device__ float g_ent[BB * SS];
__device__ int   g_sel[BB];
__device__ int   g_ord[BB * SS];         // logical pos -> physical row
// attention precomputes + fused buffers
__device__ float g_fckwT[EE * EE];
__device__ float g_fcqwT[EE * EE];
__device__ float g_W2[RR * EE];
__device__ float g_Mx[EE * EE];
__device__ float g_c2[RR + 4];
__device__ float g_v1[EE];
__device__ float g_c0[1];
__device__ float g_su[BB * NSU];

// ================= setup =================
__global__ void k_prep(const float* __restrict__ bih, const float* __restrict__ bhh,
                       const float* __restrict__ fcwv, const float* __restrict__ fcbv,
                       const float* __restrict__ fcqb, const float* __restrict__ fckb) {
    int i = blockIdx.x * blockDim.x + threadIdx.x;   // 2048
    if (i < G4) g_blstm[i] = bih[i] + bhh[i];
    if (i < EE) {
        g_fcw[i] = fcwv[i];
        g_qbias[i] = fcqb[i];
        g_qbias[EE + i] = fckb[i];
    }
    if (i == 0) g_fcw[EE] = fcbv[0];
    if (i < BB * SS) g_ord[i] = i;
}

// gate-interleave reorder: original row n = gate*512+e  ->  row n' = 4e+gate
__global__ void k_reord(const float* __restrict__ wih, const float* __restrict__ whh) {
    int i = blockIdx.x * blockDim.x + threadIdx.x;   // 2048*512
    if (i >= G4 * EE) return;
    int n = i >> 9;
    int k = i & (EE - 1);
    int e = n & (EE - 1);
    int gate = n >> 9;
    int np = 4 * e + gate;
    g_wihr[(size_t)np * EE + k] = wih[i];
    g_whhr[(size_t)np * EE + k] = whh[i];
    if (k == 0) g_blstmr[np] = g_blstm[n];
}

__global__ void k_gather(const int* __restrict__ tok, const float* __restrict__ emb) {
    int i = blockIdx.x * blockDim.x + threadIdx.x;
    if (i >= BB * SS * EE) return;
    int e = i & (EE - 1);
    int r = i >> 9;
    int t = tok[r];
    g_cur[i] = emb[(size_t)t * EE + e];
}

// transpose both fckw and fcqw (enables coalesced staging in kg_W2/kg_Mx)
__global__ void k_tr(const float* __restrict__ fckw, const float* __restrict__ fcqw) {
    int i = blockIdx.x * blockDim.x + threadIdx.x;   // 512*512
    if (i >= EE * EE) return;
    int ep = i >> 9;
    int f = i & (EE - 1);
    g_fckwT[(size_t)f * EE + ep] = fckw[(size_t)ep * EE + f];
    g_fcqwT[(size_t)f * EE + ep] = fcqw[(size_t)ep * EE + f];
}

__global__ __launch_bounds__(512) void k_vprep(const float* __restrict__ fcqw, const float* __restrict__ fckw) {
    __shared__ float sh[512];
    int t = threadIdx.x;
    int blk = blockIdx.x;
    if (blk == 0) {
        float acc = 0.f;
        for (int ep = 0; ep < EE; ep++)
            acc += g_qbias[ep] * fckw[(size_t)ep * EE + t] + g_qbias[EE + ep] * fcqw[(size_t)ep * EE + t];
        g_v1[t] = acc;
    } else if (blk == 1) {
        sh[t] = g_qbias[t] * g_qbias[EE + t];
        __syncthreads();
        for (int s = 256; s > 0; s >>= 1) { if (t < s) sh[t] += sh[t + s]; __syncthreads(); }
        if (t == 0) g_c0[0] = sh[0];
    } else {
        int k = blk - 2;
        sh[t] = g_Krel[(size_t)k * EE + t] * g_qbias[t];
        __syncthreads();
        for (int s = 256; s > 0; s >>= 1) { if (t < s) sh[t] += sh[t + s]; __syncthreads(); }
        if (t == 0) g_c2[k] = sh[0];
    }
}

// ====== fp32 GEMM tile core (setup GEMMs), LDS double-buffered (1 barrier/phase) ======
#define TM 32
#define TN 64
#define TK 32
__device__ __forceinline__ void gemm_dev(
    const float* __restrict__ A, int lda,
    const float* __restrict__ W, int ldw,
    const float* __restrict__ bias, const float* __restrict__ Dadd, int ldd,
    float* __restrict__ C, int ldc, int M, int N, int K)
{
    __shared__ __align__(16) float As[2][TK][TM + 2];
    __shared__ __align__(16) float Ws[2][TK][TN + 4];
    int tid = threadIdx.x;
    int mt = blockIdx.y * TM;
    int nt = blockIdx.x * TN;
    int tr = tid >> 4;
    int tc = tid & 15;
    float acc[2][4] = {{0.f,0.f,0.f,0.f},{0.f,0.f,0.f,0.f}};

    int ea = tid * 4;
    int ra = ea >> 5;
    int ka = ea & 31;
    int gmA = mt + ra;
    bool rokA = gmA < M;
    const float* Arow = A + (size_t)(rokA ? gmA : 0) * lda;
    int ew = tid * 8;
    int rw = ew >> 5;
    int kw = ew & 31;
    int gnW = nt + rw;
    bool rokW = gnW < N;
    const float* Wrow = W + (size_t)(rokW ? gnW : 0) * ldw;

    float4 pa = {0,0,0,0}, pw0 = {0,0,0,0}, pw1 = {0,0,0,0};
    if (rokA) pa = *(const float4*)&Arow[ka];
    if (rokW) { pw0 = *(const float4*)&Wrow[kw]; pw1 = *(const float4*)&Wrow[kw + 4]; }
    As[0][ka + 0][ra] = pa.x; As[0][ka + 1][ra] = pa.y; As[0][ka + 2][ra] = pa.z; As[0][ka + 3][ra] = pa.w;
    Ws[0][kw + 0][rw] = pw0.x; Ws[0][kw + 1][rw] = pw0.y; Ws[0][kw + 2][rw] = pw0.z; Ws[0][kw + 3][rw] = pw0.w;
    Ws[0][kw + 4][rw] = pw1.x; Ws[0][kw + 5][rw] = pw1.y; Ws[0][kw + 6][rw] = pw1.z; Ws[0][kw + 7][rw] = pw1.w;
    __syncthreads();

    int P = K / TK;
    for (int p = 0; p < P; p++) {
        int cur = p & 1;
        bool more = (p + 1) < P;
        if (more) {
            int k2 = (p + 1) * TK;
            if (rokA) pa = *(const float4*)&Arow[k2 + ka];
            if (rokW) { pw0 = *(const float4*)&Wrow[k2 + kw]; pw1 = *(const float4*)&Wrow[k2 + kw + 4]; }
        }
        #pragma unroll
        for (int kk = 0; kk < TK; kk++) {
            const float2 a = *(const float2*)&As[cur][kk][2 * tr];
            const float4 w = *(const float4*)&Ws[cur][kk][4 * tc];
            acc[0][0] += a.x * w.x; acc[0][1] += a.x * w.y; acc[0][2] += a.x * w.z; acc[0][3] += a.x * w.w;
            acc[1][0] += a.y * w.x; acc[1][1] += a.y * w.y; acc[1][2] += a.y * w.z; acc[1][3] += a.y * w.w;
        }
        if (more) {
            int nxt = cur ^ 1;
            As[nxt][ka + 0][ra] = pa.x; As[nxt][ka + 1][ra] = pa.y; As[nxt][ka + 2][ra] = pa.z; As[nxt][ka + 3][ra] = pa.w;
            Ws[nxt][kw + 0][rw] = pw0.x; Ws[nxt][kw + 1][rw] = pw0.y; Ws[nxt][kw + 2][rw] = pw0.z; Ws[nxt][kw + 3][rw] = pw0.w;
            Ws[nxt][kw + 4][rw] = pw1.x; Ws[nxt][kw + 5][rw] = pw1.y; Ws[nxt][kw + 6][rw] = pw1.z; Ws[nxt][kw + 7][rw] = pw1.w;
        }
        __syncthreads();
    }
    #pragma unroll
    for (int i = 0; i < 2; i++) {
        int gm = mt + 2 * tr + i;
        if (gm >= M) continue;
        #pragma unroll
        for (int j = 0; j < 4; j++) {
            int gn = nt + 4 * tc + j;
            if (gn >= N) continue;
            float v = (i == 0) ? ((j == 0) ? acc[0][0] : (j == 1) ? acc[0][1] : (j == 2) ? acc[0][2] : acc[0][3])
                               : ((j == 0) ? acc[1][0] : (j == 1) ? acc[1][1] : (j == 2) ? acc[1][2] : acc[1][3]);
            if (bias) v += bias[gn];
            if (Dadd) v += Dadd[(size_t)gm * ldd + gn];
            C[(size_t)gm * ldc + gn] = v;
        }
    }
}

// ============ big fused fp32 GEMM: 128x64 tile, 8x4 micro, 2 blocks/CU ============
// ROUND-7 PROVEN FORM (84 us, 72 VGPR, no spill). Round 8's 128x128 dbuf spilled
// (VGPR 256, WRITE_SIZE 493 MB) — do not widen the accumulator past 8x4 here.
// grid (32,16) = 512 blocks so 2 blocks/CU overlap staging and FMA phases.
// MODE 0: G = cur@wihr + b, fused h1/c1 epilogue (M=2048).
// MODE 1: g2 = h1@whhr + G[row+1], fused h2 epilogue, g2 never stored (M=2047).
#define UM 128
#define UN 64
#define UK 32
template<int MODE>
__global__ __launch_bounds__(256) void kg_bigF() {
    __shared__ __align__(16) float As[UK][UM + 4];   // stride 132 floats
    __shared__ __align__(16) float Ws[UK][UN + 4];   // stride 68 floats
    const float* __restrict__ A = (MODE == 0) ? g_cur : g_h1;
    const float* __restrict__ W = (MODE == 0) ? g_wihr : g_whhr;
    const int M = (MODE == 0) ? (BB * SS) : NPAIR;
    int tid = threadIdx.x;          // 256
    int mt = blockIdx.y * UM;
    int nt = blockIdx.x * UN;
    int tr = tid >> 4;              // 0..15
    int tc = tid & 15;              // 0..15
    float acc[8][4] = {};

    int ra = tid & 127;             // A row within tile
    int ka = (tid >> 7) << 4;       // 0 or 16: 16 consecutive k per thread (A)
    int gmA = mt + ra;
    bool rokA = gmA < M;
    const float* Arow = A + (size_t)(rokA ? gmA : 0) * EE;
    int rw = tid & 63;              // W row within tile
    int kw = (tid >> 6) << 3;       // 0,8,16,24: 8 consecutive k per thread (W)
    const float* Wrow = W + (size_t)(nt + rw) * EE;   // N = 2048 always full

    float4 pa[4] = {};
    float4 pw[2];
    #pragma unroll
    for (int j = 0; j < 4; j++) if (rokA) pa[j] = *(const float4*)&Arow[ka + 4 * j];
    #pragma unroll
    for (int j = 0; j < 2; j++) pw[j] = *(const float4*)&Wrow[kw + 4 * j];

    for (int kt = 0; kt < EE; kt += UK) {
        #pragma unroll
        for (int j = 0; j < 4; j++) {
            As[ka + 4 * j + 0][ra] = pa[j].x;
            As[ka + 4 * j + 1][ra] = pa[j].y;
            As[ka + 4 * j + 2][ra] = pa[j].z;
            As[ka + 4 * j + 3][ra] = pa[j].w;
        }
        #pragma unroll
        for (int j = 0; j < 2; j++) {
            Ws[kw + 4 * j + 0][rw] = pw[j].x;
            Ws[kw + 4 * j + 1][rw] = pw[j].y;
            Ws[kw + 4 * j + 2][rw] = pw[j].z;
            Ws[kw + 4 * j + 3][rw] = pw[j].w;
        }
        __syncthreads();
        if (kt + UK < EE) {
            int k2 = kt + UK;
            #pragma unroll
            for (int j = 0; j < 4; j++) if (rokA) pa[j] = *(const float4*)&Arow[k2 + ka + 4 * j];
            #pragma unroll
            for (int j = 0; j < 2; j++) pw[j] = *(const float4*)&Wrow[k2 + kw + 4 * j];
        }
        #pragma unroll
        for (int kk = 0; kk < UK; kk++) {
            const float4 aA = *(const float4*)&As[kk][4 * tr];
            const float4 aB = *(const float4*)&As[kk][64 + 4 * tr];
            const float4 w4 = *(const float4*)&Ws[kk][4 * tc];
            const float am[8] = {aA.x, aA.y, aA.z, aA.w, aB.x, aB.y, aB.z, aB.w};
            const float wn[4] = {w4.x, w4.y, w4.z, w4.w};
            #pragma unroll
            for (int i = 0; i < 8; i++)
                #pragma unroll
                for (int j = 0; j < 4; j++)
                    acc[i][j] += am[i] * wn[j];
        }
        __syncthreads();
    }

    // fused epilogue: cols nt+4tc..+3 are one complete gate quad (e0)
    int c0 = nt + 4 * tc;
    int e0 = (nt >> 2) + tc;
    #pragma unroll
    for (int ri = 0; ri < 8; ri++) {
        int row = (ri < 4) ? (4 * tr + ri) : (60 + 4 * tr + ri);
        int gm = mt + row;
        if (gm >= M) continue;
        float qx = acc[ri][0], qy = acc[ri][1], qz = acc[ri][2], qw = acc[ri][3];
        if (MODE == 0) {
            const float4 b4 = *(const float4*)&g_blstmr[c0];
            qx += b4.x; qy += b4.y; qz += b4.z; qw += b4.w;
            float4 o = {qx, qy, qz, qw};
            *(float4*)&g_G[(size_t)gm * G4 + c0] = o;
            float cA = sigm(qx) * tanhf(qz);
            g_c1[(size_t)gm * EE + e0] = cA;
            g_h1[(size_t)gm * EE + e0] = sigm(qw) * tanhf(cA);
        } else {
            const float4 d4 = *(const float4*)&g_G[(size_t)(gm + 1) * G4 + c0];
            qx += d4.x; qy += d4.y; qz += d4.z; qw += d4.w;
            float c1v = g_c1[(size_t)gm * EE + e0];
            float cA = sigm(qy) * c1v + sigm(qx) * tanhf(qz);
            g_h2[(size_t)gm * EE + e0] = sigm(qw) * tanhf(cA);
        }
    }
}

// ---- full GEMM wrappers (attention precompute; all coalesced row-major W) ----
__global__ __launch_bounds__(256) void kg_Krel(const float* __restrict__ emb, const float* __restrict__ fckw) {
    gemm_dev(emb, EE, fckw, EE, g_qbias + EE, nullptr, 0, g_Krel, EE, RR, EE, EE);
}
__global__ __launch_bounds__(256) void kg_W2() {
    gemm_dev(g_Krel, EE, g_fcqwT, EE, nullptr, nullptr, 0, g_W2, EE, RR, EE, EE);
}
__global__ __launch_bounds__(256) void kg_Mx() {
    gemm_dev(g_fckwT, EE, g_fcqwT, EE, nullptr, nullptr, 0, g_Mx, EE, EE, EE, EE);
}

// ---- init score: raw dot h2 . fcw  (sigmoid+bias monotone -> argmax-equivalent) ----
__global__ __launch_bounds__(256) void k_scI() {
    int m = blockIdx.x;                 // 0..2046
    int t = threadIdx.x;
    __shared__ float red[256];
    const float* h = g_h2 + (size_t)m * EE;
    float part = h[t] * g_fcw[t] + h[t + 256] * g_fcw[t + 256];
    red[t] = part;
    __syncthreads();
    for (int s = 128; s > 0; s >>= 1) { if (t < s) red[t] += red[t + s]; __syncthreads(); }
    if (t == 0) g_sc[m] = red[0];
}

// ---- per-iter score for the 2 changed pairs ----
__global__ __launch_bounds__(256) void k_scP(int L) {
    int m = blockIdx.x;                 // 0..255
    int b = m >> 1;
    int tcand = m & 1;
    int s = g_sel[b];
    int p = s - 1 + tcand;
    bool valid = tcand == 0 ? (s >= 1) : (s <= L - 3);
    if (!valid) return;
    int physL = g_ord[b * SS + p];
    int t = threadIdx.x;
    __shared__ float red[256];
    const float* h = g_h2 + (size_t)physL * EE;
    float part = h[t] * g_fcw[t] + h[t + 256] * g_fcw[t + 256];
    red[t] = part;
    __syncthreads();
    for (int s2 = 128; s2 > 0; s2 >>= 1) { if (t < s2) red[t] += red[t + s2]; __syncthreads(); }
    if (t == 0) g_sc[b * SS + p] = red[0];
}

// ---- fused argmax + scores|u GEMM (double-buffered) ----
__global__ __launch_bounds__(256) void kg_su(int P) {
    __shared__ __align__(16) float As[2][TK][TM + 2];
    __shared__ __align__(16) float Ws[2][TK][TN + 4];
    __shared__ int s_phys[TM];
    int tid = threadIdx.x;
    int mt = blockIdx.y * TM;
    int nt = blockIdx.x * TN;
    int tr = tid >> 4;
    int tc = tid & 15;
    float acc[2][4] = {{0.f,0.f,0.f,0.f},{0.f,0.f,0.f,0.f}};

    if (tid < TM) {
        int b = mt + tid;                    // M = BB exact
        float best = -1e30f; int bi = 0;
        for (int p = 0; p < P; p++) {
            float v = g_sc[b * SS + p];
            if (v > best) { best = v; bi = p; }
        }
        s_phys[tid] = g_ord[b * SS + bi];
        if (blockIdx.x == 0) g_sel[b] = bi;
    }
    __syncthreads();

    int ea = tid * 4;
    int ra = ea >> 5;
    int ka = ea & 31;
    const float* Arow = g_h2 + (size_t)s_phys[ra] * EE;
    int ew = tid * 8;
    int rw = ew >> 5;
    int kw = ew & 31;
    int gnW = nt + rw;
    bool rokW = gnW < NSU;
    const float* Wrow = nullptr;
    if (rokW) Wrow = (gnW < RR) ? (g_W2 + (size_t)gnW * EE) : (g_Mx + (size_t)(gnW - RR) * EE);

    float4 pa = *(const float4*)&Arow[ka];
    float4 pw0 = {0,0,0,0}, pw1 = {0,0,0,0};
    if (rokW) { pw0 = *(const float4*)&Wrow[kw]; pw1 = *(const float4*)&Wrow[kw + 4]; }
    As[0][ka + 0][ra] = pa.x; As[0][ka + 1][ra] = pa.y; As[0][ka + 2][ra] = pa.z; As[0][ka + 3][ra] = pa.w;
    Ws[0][kw + 0][rw] = pw0.x; Ws[0][kw + 1][rw] = pw0.y; Ws[0][kw + 2][rw] = pw0.z; Ws[0][kw + 3][rw] = pw0.w;
    Ws[0][kw + 4][rw] = pw1.x; Ws[0][kw + 5][rw] = pw1.y; Ws[0][kw + 6][rw] = pw1.z; Ws[0][kw + 7][rw] = pw1.w;
    __syncthreads();

    const int NP = EE / TK;
    for (int p = 0; p < NP; p++) {
        int cur = p & 1;
        bool more = (p + 1) < NP;
        if (more) {
            int k2 = (p + 1) * TK;
            pa = *(const float4*)&Arow[k2 + ka];
            if (rokW) { pw0 = *(const float4*)&Wrow[k2 + kw]; pw1 = *(const float4*)&Wrow[k2 + kw + 4]; }
        }
        #pragma unroll
        for (int kk = 0; kk < TK; kk++) {
            const float2 a = *(const float2*)&As[cur][kk][2 * tr];
            const float4 w = *(const float4*)&Ws[cur][kk][4 * tc];
            acc[0][0] += a.x * w.x; acc[0][1] += a.x * w.y; acc[0][2] += a.x * w.z; acc[0][3] += a.x * w.w;
            acc[1][0] += a.y * w.x; acc[1][1] += a.y * w.y; acc[1][2] += a.y * w.z; acc[1][3] += a.y * w.w;
        }
        if (more) {
            int nxt = cur ^ 1;
            As[nxt][ka + 0][ra] = pa.x; As[nxt][ka + 1][ra] = pa.y; As[nxt][ka + 2][ra] = pa.z; As[nxt][ka + 3][ra] = pa.w;
            Ws[nxt][kw + 0][rw] = pw0.x; Ws[nxt][kw + 1][rw] = pw0.y; Ws[nxt][kw + 2][rw] = pw0.z; Ws[nxt][kw + 3][rw] = pw0.w;
            Ws[nxt][kw + 4][rw] = pw1.x; Ws[nxt][kw + 5][rw] = pw1.y; Ws[nxt][kw + 6][rw] = pw1.z; Ws[nxt][kw + 7][rw] = pw1.w;
        }
        __syncthreads();
    }
    #pragma unroll
    for (int i = 0; i < 2; i++) {
        int gm = mt + 2 * tr + i;
        #pragma unroll
        for (int j = 0; j < 4; j++) {
            int gn = nt + 4 * tc + j;
            if (gn >= NSU) continue;
            float v = (i == 0) ? ((j == 0) ? acc[0][0] : (j == 1) ? acc[0][1] : (j == 2) ? acc[0][2] : acc[0][3])
                               : ((j == 0) ? acc[1][0] : (j == 1) ? acc[1][1] : (j == 2) ? acc[1][2] : acc[1][3]);
            g_su[(size_t)gm * NSU + gn] = v + (gn < RR ? g_c2[gn] : 0.f);
        }
    }
}

// ---- incremental fused GEMM: G/h1/c1 for merged row; M=BB (double-buffered) ----
__global__ __launch_bounds__(256) void kg_GiF() {
    __shared__ __align__(16) float As[2][TK][TM + 2];
    __shared__ __align__(16) float Ws[2][TK][TN + 4];
    __shared__ int s_phys[TM];
    int tid = threadIdx.x;
    int mt = blockIdx.y * TM;
    int nt = blockIdx.x * TN;
    int tr = tid >> 4;
    int tc = tid & 15;
    float acc[2][4] = {{0.f,0.f,0.f,0.f},{0.f,0.f,0.f,0.f}};

    if (tid < TM) {
        int b = mt + tid;
        s_phys[tid] = g_ord[b * SS + g_sel[b]];
    }
    __syncthreads();

    int ea = tid * 4;
    int ra = ea >> 5;
    int ka = ea & 31;
    const float* Arow = g_cur + (size_t)s_phys[ra] * EE;
    int ew = tid * 8;
    int rw = ew >> 5;
    int kw = ew & 31;
    const float* Wrow = g_wihr + (size_t)(nt + rw) * EE;

    float4 pa = *(const float4*)&Arow[ka];
    float4 pw0 = *(const float4*)&Wrow[kw];
    float4 pw1 = *(const float4*)&Wrow[kw + 4];
    As[0][ka + 0][ra] = pa.x; As[0][ka + 1][ra] = pa.y; As[0][ka + 2][ra] = pa.z; As[0][ka + 3][ra] = pa.w;
    Ws[0][kw + 0][rw] = pw0.x; Ws[0][kw + 1][rw] = pw0.y; Ws[0][kw + 2][rw] = pw0.z; Ws[0][kw + 3][rw] = pw0.w;
    Ws[0][kw + 4][rw] = pw1.x; Ws[0][kw + 5][rw] = pw1.y; Ws[0][kw + 6][rw] = pw1.z; Ws[0][kw + 7][rw] = pw1.w;
    __syncthreads();

    const int NP = EE / TK;
    for (int p = 0; p < NP; p++) {
        int cur = p & 1;
        bool more = (p + 1) < NP;
        if (more) {
            int k2 = (p + 1) * TK;
            pa = *(const float4*)&Arow[k2 + ka];
            pw0 = *(const float4*)&Wrow[k2 + kw];
            pw1 = *(const float4*)&Wrow[k2 + kw + 4];
        }
        #pragma unroll
        for (int kk = 0; kk < TK; kk++) {
            const float2 a = *(const float2*)&As[cur][kk][2 * tr];
            const float4 w = *(const float4*)&Ws[cur][kk][4 * tc];
            acc[0][0] += a.x * w.x; acc[0][1] += a.x * w.y; acc[0][2] += a.x * w.z; acc[0][3] += a.x * w.w;
            acc[1][0] += a.y * w.x; acc[1][1] += a.y * w.y; acc[1][2] += a.y * w.z; acc[1][3] += a.y * w.w;
        }
        if (more) {
            int nxt = cur ^ 1;
            As[nxt][ka + 0][ra] = pa.x; As[nxt][ka + 1][ra] = pa.y; As[nxt][ka + 2][ra] = pa.z; As[nxt][ka + 3][ra] = pa.w;
            Ws[nxt][kw + 0][rw] = pw0.x; Ws[nxt][kw + 1][rw] = pw0.y; Ws[nxt][kw + 2][rw] = pw0.z; Ws[nxt][kw + 3][rw] = pw0.w;
            Ws[nxt][kw + 4][rw] = pw1.x; Ws[nxt][kw + 5][rw] = pw1.y; Ws[nxt][kw + 6][rw] = pw1.z; Ws[nxt][kw + 7][rw] = pw1.w;
        }
        __syncthreads();
    }
    int c0 = nt + 4 * tc;
    int e0 = (nt >> 2) + tc;
    const float4 b4 = *(const float4*)&g_blstmr[c0];
    #pragma unroll
    for (int i = 0; i < 2; i++) {
        int phys = s_phys[2 * tr + i];
        float qx = acc[i][0] + b4.x;
        float qy = acc[i][1] + b4.y;
        float qz = acc[i][2] + b4.z;
        float qw = acc[i][3] + b4.w;
        float4 o = {qx, qy, qz, qw};
        *(float4*)&g_G[(size_t)phys * G4 + c0] = o;
        float cA = sigm(qx) * tanhf(qz);
        g_c1[(size_t)phys * EE + e0] = cA;
        g_h1[(size_t)phys * EE + e0] = sigm(qw) * tanhf(cA);
    }
}

// ---- incremental fused GEMM: h2 for 2 candidate pairs/batch; M=2*BB (double-buffered) ----
__global__ __launch_bounds__(256) void kg_g2iF(int L) {
    __shared__ __align__(16) float As[2][TK][TM + 2];
    __shared__ __align__(16) float Ws[2][TK][TN + 4];
    __shared__ int s_physA[TM];
    __shared__ int s_physD[TM];
    __shared__ int s_val[TM];
    int tid = threadIdx.x;
    int mt = blockIdx.y * TM;
    int nt = blockIdx.x * TN;
    int tr = tid >> 4;
    int tc = tid & 15;
    float acc[2][4] = {{0.f,0.f,0.f,0.f},{0.f,0.f,0.f,0.f}};

    if (tid < TM) {
        int gm = mt + tid;
        int b = gm >> 1;
        int tcand = gm & 1;
        int s = g_sel[b];
        int p = min(max(s - 1 + tcand, 0), 14);
        s_physA[tid] = g_ord[b * SS + p];
        s_physD[tid] = g_ord[b * SS + p + 1];
        s_val[tid] = tcand == 0 ? (s >= 1) : (s <= L - 3);
    }
    __syncthreads();

    int ea = tid * 4;
    int ra = ea >> 5;
    int ka = ea & 31;
    const float* Arow = g_h1 + (size_t)s_physA[ra] * EE;
    int ew = tid * 8;
    int rw = ew >> 5;
    int kw = ew & 31;
    const float* Wrow = g_whhr + (size_t)(nt + rw) * EE;

    float4 pa = *(const float4*)&Arow[ka];
    float4 pw0 = *(const float4*)&Wrow[kw];
    float4 pw1 = *(const float4*)&Wrow[kw + 4];
    As[0][ka + 0][ra] = pa.x; As[0][ka + 1][ra] = pa.y; As[0][ka + 2][ra] = pa.z; As[0][ka + 3][ra] = pa.w;
    Ws[0][kw + 0][rw] = pw0.x; Ws[0][kw + 1][rw] = pw0.y; Ws[0][kw + 2][rw] = pw0.z; Ws[0][kw + 3][rw] = pw0.w;
    Ws[0][kw + 4][rw] = pw1.x; Ws[0][kw + 5][rw] = pw1.y; Ws[0][kw + 6][rw] = pw1.z; Ws[0][kw + 7][rw] = pw1.w;
    __syncthreads();

    const int NP = EE / TK;
    for (int p = 0; p < NP; p++) {
        int cur = p & 1;
        bool more = (p + 1) < NP;
        if (more) {
            int k2 = (p + 1) * TK;
            pa = *(const float4*)&Arow[k2 + ka];
            pw0 = *(const float4*)&Wrow[k2 + kw];
            pw1 = *(const float4*)&Wrow[k2 + kw + 4];
        }
        #pragma unroll
        for (int kk = 0; kk < TK; kk++) {
            const float2 a = *(const float2*)&As[cur][kk][2 * tr];
            const float4 w = *(const float4*)&Ws[cur][kk][4 * tc];
            acc[0][0] += a.x * w.x; acc[0][1] += a.x * w.y; acc[0][2] += a.x * w.z; acc[0][3] += a.x * w.w;
            acc[1][0] += a.y * w.x; acc[1][1] += a.y * w.y; acc[1][2] += a.y * w.z; acc[1][3] += a.y * w.w;
        }
        if (more) {
            int nxt = cur ^ 1;
            As[nxt][ka + 0][ra] = pa.x; As[nxt][ka + 1][ra] = pa.y; As[nxt][ka + 2][ra] = pa.z; As[nxt][ka + 3][ra] = pa.w;
            Ws[nxt][kw + 0][rw] = pw0.x; Ws[nxt][kw + 1][rw] = pw0.y; Ws[nxt][kw + 2][rw] = pw0.z; Ws[nxt][kw + 3][rw] = pw0.w;
            Ws[nxt][kw + 4][rw] = pw1.x; Ws[nxt][kw + 5][rw] = pw1.y; Ws[nxt][kw + 6][rw] = pw1.z; Ws[nxt][kw + 7][rw] = pw1.w;
        }
        __syncthreads();
    }
    int c0 = nt + 4 * tc;
    int e0 = (nt >> 2) + tc;
    #pragma unroll
    for (int i = 0; i < 2; i++) {
        int r = 2 * tr + i;
        if (!s_val[r]) continue;
        int pA = s_physA[r];
        int pD = s_physD[r];
        const float4 d4 = *(const float4*)&g_G[(size_t)pD * G4 + c0];
        float qx = acc[i][0] + d4.x;
        float qy = acc[i][1] + d4.y;
        float qz = acc[i][2] + d4.z;
        float qw = acc[i][3] + d4.w;
        float c1v = g_c1[(size_t)pA * EE + e0];
        float cA = sigm(qy) * c1v + sigm(qx) * tanhf(qz);
        g_h2[(size_t)pA * EE + e0] = sigm(qw) * tanhf(cA);
    }
}

// ================= fused softmax + entropy + merged + ord-update (+final output) =================
__global__ __launch_bounds__(512) void k_smu(int col, int finalFlag, int L,
                                             const float* __restrict__ emb, float* __restrict__ out) {
    int b = blockIdx.x;
    int t = threadIdx.x;      // 0..511
    __shared__ float sh[512];
    __shared__ float srow[NSC];
    __shared__ float s_p500;
    const float* su = g_su + (size_t)b * NSU;
    int s = g_sel[b];
    int phys = g_ord[b * SS + s];
    const float* h2row = g_h2 + (size_t)phys * EE;
    const float isq = 0.044194173824159216f;   // 1/sqrt(512)

    float hv = h2row[t];
    sh[t] = hv * (su[RR + t] + g_v1[t]);
    __syncthreads();
    for (int ss = 256; ss > 0; ss >>= 1) { if (t < ss) sh[t] += sh[t + ss]; __syncthreads(); }
    if (t == 0) srow[RR] = (sh[0] + g_c0[0]) * isq;
    __syncthreads();
    if (t < RR) srow[t] = su[t] * isq;
    __syncthreads();
    float mx = (t < NSC) ? srow[t] : -1e30f;
    sh[t] = mx; __syncthreads();
    for (int ss = 256; ss > 0; ss >>= 1) { if (t < ss) sh[t] = fmaxf(sh[t], sh[t + ss]); __syncthreads(); }
    mx = sh[0]; __syncthreads();
    float zp = (t < NSC) ? expf(srow[t] - mx) : 0.f;
    sh[t] = zp; __syncthreads();
    for (int ss = 256; ss > 0; ss >>= 1) { if (t < ss) sh[t] += sh[t + ss]; __syncthreads(); }
    float lse = mx + logf(sh[0]);
    __syncthreads();
    float pb = (t < NSC) ? expf(srow[t] - lse) : 0.f;
    float ep = (t < NSC) ? pb * (lse - srow[t]) : 0.f;
    if (finalFlag && t < NSC) out[(size_t)b * NSC + t] = srow[t];
    sh[t] = ep; __syncthreads();
    for (int ss = 256; ss > 0; ss >>= 1) { if (t < ss) sh[t] += sh[t + ss]; __syncthreads(); }
    if (finalFlag) {
        if (t < 16) {
            float v = (t == 15) ? sh[0] : ((t == 14) ? 0.f : g_ent[b * SS + t]);
            out[OUT0 + b * 16 + t] = v;
        }
        return;
    }
    if (t == 0) g_ent[b * SS + col] = sh[0];

    __syncthreads();
    if (t < NSC) srow[t] = pb;
    if (t == RR) s_p500 = pb;
    __syncthreads();
    float macc = 0.f;
    #pragma unroll 4
    for (int k = 0; k < RR; k++) macc += srow[k] * emb[(size_t)k * EE + t];
    g_cur[(size_t)phys * EE + t] = macc + s_p500 * hv;
    if (t == 0) {
        for (int j = s + 1; j <= L - 2; j++) g_ord[b * SS + j] = g_ord[b * SS + j + 1];
        for (int pp = s + 1; pp <= L - 3; pp++) g_sc[b * SS + pp] = g_sc[b * SS + pp + 1];
    }
}

// ================= host launch =================
extern "C" void kernel_launch(void* const* d_in, const int* in_sizes, int n_in,
                              void* d_out, int out_size, void* d_ws, size_t ws_size,
                              hipStream_t stream) {
    const int*   tokens = (const int*)d_in[0];
    const float* emb    = (const float*)d_in[1];
    const float* wih    = (const float*)d_in[2];
    const float* whh    = (const float*)d_in[3];
    const float* bih    = (const float*)d_in[4];
    const float* bhh    = (const float*)d_in[5];
    const float* fcwv   = (const float*)d_in[6];
    const float* fcbv   = (const float*)d_in[7];
    const float* fcqw   = (const float*)d_in[8];
    const float* fcqb   = (const float*)d_in[9];
    const float* fckw   = (const float*)d_in[10];
    const float* fckb   = (const float*)d_in[11];
    float* out = (float*)d_out;

    auto grid32 = [](int M, int N) { return dim3((unsigned)((N + TN - 1) / TN), (unsigned)((M + TM - 1) / TM)); };

    // ---- setup + attention precomputes (once) ----
    k_prep<<<dim3(8), dim3(256), 0, stream>>>(bih, bhh, fcwv, fcbv, fcqb, fckb);
    k_reord<<<dim3((G4 * EE) / 256), dim3(256), 0, stream>>>(wih, whh);
    kg_Krel<<<grid32(RR, EE), dim3(256), 0, stream>>>(emb, fckw);
    k_tr<<<dim3((EE * EE + 255) / 256), dim3(256), 0, stream>>>(fckw, fcqw);
    kg_W2<<<grid32(RR, EE), dim3(256), 0, stream>>>();
    kg_Mx<<<grid32(EE, EE), dim3(256), 0, stream>>>();
    k_vprep<<<dim3(502), dim3(512), 0, stream>>>(fcqw, fckw);
    k_gather<<<dim3((BB * SS * EE + 255) / 256), dim3(256), 0, stream>>>(tokens, emb);

    // ---- initial full LSTM pass (once; identity order; fused gate epilogues) ----
    kg_bigF<0><<<dim3(32, 16), dim3(256), 0, stream>>>();
    kg_bigF<1><<<dim3(32, 16), dim3(256), 0, stream>>>();
    k_scI<<<dim3(NPAIR), dim3(256), 0, stream>>>();

    for (int L = SS; L >= 3; L--) {
        kg_su<<<grid32(BB, NSU), dim3(256), 0, stream>>>(L - 1);
        k_smu<<<dim3(BB), dim3(512), 0, stream>>>(SS - L, 0, L, emb, out);
        kg_GiF<<<grid32(BB, G4), dim3(256), 0, stream>>>();
        kg_g2iF<<<grid32(2 * BB, G4), dim3(256), 0, stream>>>(L);
        k_scP<<<dim3(2 * BB), dim3(256), 0, stream>>>(L);
    }

    // L == 2: pair 0's h2 is the final x; final k_smu writes scores + loss region
    kg_su<<<grid32(BB, NSU), dim3(256), 0, stream>>>(1);
    k_smu<<<dim3(BB), dim3(512), 0, stream>>>(15, 1, 2, emb, out);

    (void)in_sizes; (void)n_in; (void)out_size; (void)d_ws; (void)ws_size;
}